// Round 5
// baseline (21.540 us; speedup 1.0000x reference)
//
#include <hip/hip_runtime.h>
#include <math.h>

// BlockwiseQuantizationOptim: 1024x1024 f32, 64 blocks of 128x128, L=256, T=100.
// Closed-form softmax over uniform levels: e_l = r^|p-l|, r = exp(-100/255).
//   S  = rf*A[k] + r1f*A[j],  j = 254-k
//   W  = rf*(k*A[k]-B[k]) + r1f*((k+1)*A[j]+B[j])
// tab4[k] = (A[k], k*A[k]-B[k], A[j], (k+1)*A[j]+B[j])
// bin_mass: two ds_add_u32 fixed-point (2^23) deposits per element (u32 is the
// native-fast LDS atomic; u64/f32 paths are slow — measured R2/R4), then
// per-column geometric scans (register-local + in-wave shfl carry scan).
// Entropy: per-WG partial -> d_ws; LAST workgroup (atomicInc protocol, robust
// to poisoned init) reduces 512 partials and stores the scalar. Single kernel.
//
// dep LDS layout: idx(c,l) = (l&15)*272 + c*17 + (l>>4)  (scan-phase ~2-way)

#define NT 512
#define LVL 256
#define FXS 8388608.0f            // 2^23
#define INV_FXS (1.0f / 8388608.0f)
#define DEPIDX(c, l) ((((l) & 15) * 272) + ((c) * 17) + ((l) >> 4))

__global__ __launch_bounds__(NT)
void bq_main(const float* __restrict__ Wt,
             const float* __restrict__ wmin_in,
             const float* __restrict__ wmax_in,
             float* __restrict__ dq_out,
             float* __restrict__ partials,
             unsigned* __restrict__ cnt,
             float* __restrict__ ent_out)
{
    __shared__ float4 tab4[LVL];
    __shared__ unsigned dep[2][4352];
    __shared__ float wred[8];
    __shared__ int lastFlag;

    const int tid = threadIdx.x;
    const int wg  = blockIdx.x;
    const int n = wg >> 3, slab = wg & 7;   // block 0..63, 16-col slab 0..7

    const float LN2 = 0.69314718055994531f;
    const float L2R = -(100.0f / 255.0f) * 1.4426950408889634f;  // log2(r)
    const float r = __builtin_amdgcn_exp2f(L2R);
    const float inv1mr = 1.0f / (1.0f - r);

    if (tid < LVL) {
        const int k = tid;
        const float rk1 = __builtin_amdgcn_exp2f(L2R * (float)(k + 1));
        const float Ak = (1.0f - rk1) * inv1mr;
        const float Bk = (r - (float)(k + 1) * rk1 + (float)k * rk1 * r)
                         * (inv1mr * inv1mr);
        const float rj1 = __builtin_amdgcn_exp2f(L2R * (float)(255 - k));
        const float Aj = (1.0f - rj1) * inv1mr;
        const float Bj = (r - (float)(255 - k) * rj1 + (float)(254 - k) * rj1 * r)
                         * (inv1mr * inv1mr);
        tab4[k] = make_float4(Ak, (float)k * Ak - Bk,
                              Aj, (float)(k + 1) * Aj + Bj);
    }
    for (int q = tid; q < 2 * 4352; q += NT) (&dep[0][0])[q] = 0u;

    const float bmn = wmin_in[n], bmx = wmax_in[n];
    const float wmn = fminf(bmn, bmx - 1e-6f);
    const float wmx = fmaxf(bmx, wmn + 1e-6f);
    const float scale = wmx - wmn;
    const float invsc = 255.0f / (scale + 1e-6f);
    const float sc255 = scale * (1.0f / 255.0f);

    __syncthreads();

    // ---- phase 1: closed-form softmax + dequant + 2 u32 deposits/element
    {
        const int row = tid >> 2;              // 0..127
        const int c0  = (tid & 3) * 4;         // 0,4,8,12
        const int R = (n >> 3) * 128 + row;
        const int C = (n & 7) * 128 + slab * 16 + c0;
        const float4 x4 = *reinterpret_cast<const float4*>(Wt + (size_t)R * 1024 + C);
        float xs[4] = {x4.x, x4.y, x4.z, x4.w};
        float dq[4];
        #pragma unroll
        for (int u = 0; u < 4; ++u) {
            const float p = (xs[u] - wmn) * invsc;   // in [0,255)
            int k = (int)p; k = (k > 254) ? 254 : k;
            const float f   = p - (float)k;
            const float rf  = __builtin_amdgcn_exp2f(L2R * f);
            const float r1f = __builtin_amdgcn_exp2f(L2R * (1.0f - f));
            const float4 t = tab4[k];
            const float S  = rf * t.x + r1f * t.z;
            const float Wn = rf * t.y + r1f * t.w;
            const float invS = __builtin_amdgcn_rcpf(S);
            dq[u] = Wn * invS * sc255 + wmn;
            const int c = c0 + u;
            atomicAdd(&dep[0][DEPIDX(c, k)],     (unsigned)(rf  * invS * FXS));
            atomicAdd(&dep[1][DEPIDX(c, k + 1)], (unsigned)(r1f * invS * FXS));
        }
        float4 o4; o4.x = dq[0]; o4.y = dq[1]; o4.z = dq[2]; o4.w = dq[3];
        *reinterpret_cast<float4*>(dq_out + (size_t)R * 1024 + C) = o4;
    }
    __syncthreads();

    // ---- phase 2: geometric scans; thread = (dir, col, chunk of 16 levels)
    // reads u32 fixed-point, writes back float (disjoint per-thread ownership;
    // all 16 reads complete before writes)
    {
        const int ch  = tid & 15;              // levels [16ch, 16ch+15]
        const int col = (tid >> 4) & 15;
        const int dir = tid >> 8;              // 0: down (hi->lo), 1: up
        unsigned* au = &dep[dir][0];
        float*    af = reinterpret_cast<float*>(au);
        const int base = col * 17 + ch;
        float lv[16];
        float v = 0.0f;
        if (dir == 0) {
            #pragma unroll
            for (int i = 15; i >= 0; --i) {
                v = v * r + (float)au[i * 272 + base] * INV_FXS;
                lv[i] = v;
            }
        } else {
            #pragma unroll
            for (int i = 0; i < 16; ++i) {
                v = v * r + (float)au[i * 272 + base] * INV_FXS;
                lv[i] = v;
            }
        }
        // cross-chunk carry: weighted Hillis-Steele over 16 chunks, in-wave
        const float r16 = __builtin_amdgcn_exp2f(L2R * 16.0f);
        float u = v, rp = r16;
        #pragma unroll
        for (int s = 1; s <= 8; s <<= 1) {
            const float o = (dir == 0) ? __shfl_down(u, s, 16) : __shfl_up(u, s, 16);
            const bool ok = (dir == 0) ? (ch + s < 16) : (ch >= s);
            u += ok ? rp * o : 0.0f;
            rp *= rp;
        }
        float cv;
        if (dir == 0) cv = (ch < 15) ? __shfl_down(u, 1, 16) : 0.0f;
        else          cv = (ch > 0)  ? __shfl_up(u, 1, 16)  : 0.0f;
        float m = cv * r;
        if (dir == 0) {
            #pragma unroll
            for (int i = 15; i >= 0; --i) { af[i * 272 + base] = lv[i] + m; m *= r; }
        } else {
            #pragma unroll
            for (int i = 0; i < 16; ++i) { af[i * 272 + base] = lv[i] + m; m *= r; }
        }
    }
    __syncthreads();

    // ---- phase 3: entropy partial over this slab's 16x256 bins
    const float* d0 = reinterpret_cast<const float*>(&dep[0][0]);
    const float* d1 = reinterpret_cast<const float*>(&dep[1][0]);
    float hsum = 0.0f;
    #pragma unroll
    for (int t = 0; t < 8; ++t) {
        const int q = tid + t * NT;
        const int c = q & 15, l = q >> 4;
        const int idx = DEPIDX(c, l);
        const float b  = d0[idx] + d1[idx];
        const float ph = b * (1.0f / 16384.0f);
        hsum -= ph * (__builtin_amdgcn_logf(ph + 1e-6f) * LN2);
    }
    #pragma unroll
    for (int off = 32; off > 0; off >>= 1) hsum += __shfl_down(hsum, off);
    if ((tid & 63) == 0) wred[tid >> 6] = hsum;
    __syncthreads();

    // ---- phase 4: publish partial; LAST workgroup reduces all 512.
    // atomicInc(cnt,511): for any init >= 511 (poison 0xAAAAAAAA or steady
    // 511) the first arrival wraps to 0 and the 512th sees old==510; the
    // protocol leaves 511 behind, so every replay is exact.
    if (tid == 0) {
        float tot = 0.0f;
        #pragma unroll
        for (int w = 0; w < 8; ++w) tot += wred[w];
        partials[wg] = tot;
        __threadfence();
        const unsigned old = atomicInc(cnt, 511u);
        lastFlag = (old == 510u) ? 1 : 0;
    }
    __syncthreads();
    if (lastFlag) {
        __threadfence();   // acquire: make all WGs' partials visible
        float p = partials[tid];
        if (!(p > -1e30f && p < 1e30f)) p = 0.0f;   // sanitize vs fresh garbage
        #pragma unroll
        for (int off = 32; off > 0; off >>= 1) p += __shfl_down(p, off);
        if ((tid & 63) == 0) wred[tid >> 6] = p;
        __syncthreads();
        if (tid == 0) {
            float tot = 0.0f;
            #pragma unroll
            for (int w = 0; w < 8; ++w) tot += wred[w];
            ent_out[0] = tot;
        }
    }
}

extern "C" void kernel_launch(void* const* d_in, const int* in_sizes, int n_in,
                              void* d_out, int out_size, void* d_ws, size_t ws_size,
                              hipStream_t stream)
{
    const float* Wt  = (const float*)d_in[0];
    const float* wmn = (const float*)d_in[1];
    const float* wmx = (const float*)d_in[2];
    float* out = (float*)d_out;              // [1048576 dequant] + [1 entropy]
    float* partials = (float*)d_ws;          // 512 floats
    unsigned* cnt = (unsigned*)d_ws + 512;   // arrival counter

    bq_main<<<512, NT, 0, stream>>>(Wt, wmn, wmx, out, partials, cnt, out + 1048576);
}

// Round 6
// 12.442 us; speedup vs baseline: 1.7313x; 1.7313x over previous
//
#include <hip/hip_runtime.h>
#include <math.h>

// BlockwiseQuantizationOptim: 1024x1024 f32, 64 blocks of 128x128, L=256, T=100.
// Closed-form softmax over uniform levels: e_l = r^|p-l|, r = exp(-100/255).
//   S  = rf*A[k] + r1f*A[j],  j = 254-k
//   W  = rf*(k*A[k]-B[k]) + r1f*((k+1)*A[j]+B[j])
// tabK[k] = (A[k], k*A[k]-B[k]);  tabJ[j] = (A[j], (255-j)*A[j]+B[j])
//
// bin_mass: ONE ds_add_u32 per element, packing down-seed (level k, bits 0..15)
// and up-seed (level k+1, bits 16..31) as 8.8 fixed point. Per-bin half-sums
// <= 128*256 = 32768 < 2^16 -> no cross-half carry. u32 LDS atomic is the only
// proven-native-fast path (f32 CAS: R2 +18us; u64: R4 slow).
// Per-column geometric scans (register-local + in-wave shfl carry scan)
// reconstruct the histogram. Two-kernel finish — NO device-scope fences or
// global atomics in the hot kernel (R4/R5 regression: agent-scope release
// forces XCD-L2 writeback).
//
// dep LDS layout: idx(c,l) = (l&15)*272 + c*17 + (l>>4)  (scan-phase ~2-way)

#define NT 512
#define LVL 256
#define PSC 256.0f                // 8 fraction bits
#define INV_PSC (1.0f / 256.0f)
#define DEPIDX(c, l) ((((l) & 15) * 272) + ((c) * 17) + ((l) >> 4))
#define NDEP 4352

__global__ __launch_bounds__(NT)
void bq_main(const float* __restrict__ Wt,
             const float* __restrict__ wmin_in,
             const float* __restrict__ wmax_in,
             float* __restrict__ dq_out,
             float* __restrict__ partials)
{
    __shared__ float2 tabK[LVL];      // (A[k], k*A[k]-B[k])
    __shared__ float2 tabJ[LVL];      // (A[j], (255-j)*A[j]+B[j])
    __shared__ unsigned dep[NDEP];    // packed {lo: dn@l, hi: up@l+1}; -> D floats
    __shared__ float   arrU[NDEP];    // up-chain scan output (no init needed)
    __shared__ float wred[8];

    const int tid = threadIdx.x;
    const int wg  = blockIdx.x;
    const int n = wg >> 3, slab = wg & 7;   // block 0..63, 16-col slab 0..7

    const float LN2 = 0.69314718055994531f;
    const float L2R = -(100.0f / 255.0f) * 1.4426950408889634f;  // log2(r)
    const float r = __builtin_amdgcn_exp2f(L2R);
    const float inv1mr = 1.0f / (1.0f - r);

    if (tid < LVL) {
        const int k = tid;
        const float rk1 = __builtin_amdgcn_exp2f(L2R * (float)(k + 1)); // r^{k+1}
        const float A = (1.0f - rk1) * inv1mr;
        const float B = (r - (float)(k + 1) * rk1 + (float)k * rk1 * r)
                        * (inv1mr * inv1mr);
        tabK[k] = make_float2(A, (float)k * A - B);
        tabJ[k] = make_float2(A, (float)(255 - k) * A + B);
    }
    for (int q = tid; q < NDEP; q += NT) dep[q] = 0u;

    const float bmn = wmin_in[n], bmx = wmax_in[n];
    const float wmn = fminf(bmn, bmx - 1e-6f);
    const float wmx = fmaxf(bmx, wmn + 1e-6f);
    const float scale = wmx - wmn;
    const float invsc = 255.0f / (scale + 1e-6f);
    const float sc255 = scale * (1.0f / 255.0f);

    __syncthreads();

    // ---- phase 1: closed-form softmax + dequant + 1 packed u32 deposit/elem
    {
        const int row = tid >> 2;              // 0..127
        const int c0  = (tid & 3) * 4;         // 0,4,8,12
        const int R = (n >> 3) * 128 + row;
        const int C = (n & 7) * 128 + slab * 16 + c0;
        const float4 x4 = *reinterpret_cast<const float4*>(Wt + (size_t)R * 1024 + C);
        float xs[4] = {x4.x, x4.y, x4.z, x4.w};
        float dq[4];
        #pragma unroll
        for (int u = 0; u < 4; ++u) {
            const float p = (xs[u] - wmn) * invsc;   // in [0,255)
            int k = (int)p; k = (k > 254) ? 254 : k;
            const float f   = p - (float)k;
            const float rf  = __builtin_amdgcn_exp2f(L2R * f);
            const float r1f = __builtin_amdgcn_exp2f(L2R * (1.0f - f));
            const float2 K = tabK[k];
            const float2 J = tabJ[254 - k];
            const float S  = rf * K.x + r1f * J.x;
            const float Wn = rf * K.y + r1f * J.y;
            const float invS = __builtin_amdgcn_rcpf(S);
            dq[u] = Wn * invS * sc255 + wmn;
            const int c = c0 + u;
            const unsigned dn = (unsigned)(rf  * invS * PSC + 0.5f);
            const unsigned up = (unsigned)(r1f * invS * PSC + 0.5f);
            atomicAdd(&dep[DEPIDX(c, k)], dn | (up << 16));
        }
        float4 o4; o4.x = dq[0]; o4.y = dq[1]; o4.z = dq[2]; o4.w = dq[3];
        *reinterpret_cast<float4*>(dq_out + (size_t)R * 1024 + C) = o4;
    }
    __syncthreads();

    // ---- phase 2: geometric scans; thread = (dir, col, chunk of 16 levels)
    // dir0: D[l] = sum_{k>=l} dn_k r^{k-l}  (reads lo halves, hi->lo)
    // dir1: U[l] = sum_{j<=l} up_j r^{l-j}  (up-seed for level j is hi half of
    //        word j-1; reads hi halves, lo->hi)
    // All reads complete before the mid-barrier; then dir0 overwrites dep as
    // float D, dir1 writes arrU.
    {
        const int ch  = tid & 15;              // levels [16ch, 16ch+15]
        const int col = (tid >> 4) & 15;
        const int dir = tid >> 8;              // 0: down, 1: up
        float lv[16];
        float v = 0.0f;
        if (dir == 0) {
            #pragma unroll
            for (int i = 15; i >= 0; --i) {
                const int l = ch * 16 + i;
                v = v * r + (float)(dep[DEPIDX(col, l)] & 0xffffu) * INV_PSC;
                lv[i] = v;
            }
        } else {
            #pragma unroll
            for (int i = 0; i < 16; ++i) {
                const int l = ch * 16 + i;
                const unsigned w = (l > 0) ? dep[DEPIDX(col, l - 1)] : 0u;
                v = v * r + (float)(w >> 16) * INV_PSC;
                lv[i] = v;
            }
        }
        // cross-chunk carry: weighted Hillis-Steele over 16 chunks, in-wave
        const float r16 = __builtin_amdgcn_exp2f(L2R * 16.0f);
        float u = v, rp = r16;
        #pragma unroll
        for (int s = 1; s <= 8; s <<= 1) {
            const float o = (dir == 0) ? __shfl_down(u, s, 16) : __shfl_up(u, s, 16);
            const bool ok = (dir == 0) ? (ch + s < 16) : (ch >= s);
            u += ok ? rp * o : 0.0f;
            rp *= rp;
        }
        float cv;
        if (dir == 0) cv = (ch < 15) ? __shfl_down(u, 1, 16) : 0.0f;
        else          cv = (ch > 0)  ? __shfl_up(u, 1, 16)  : 0.0f;

        __syncthreads();   // all packed reads done before dep is overwritten

        float* fD = reinterpret_cast<float*>(&dep[0]);
        float m = cv * r;
        if (dir == 0) {
            #pragma unroll
            for (int i = 15; i >= 0; --i) {
                const int l = ch * 16 + i;
                fD[DEPIDX(col, l)] = lv[i] + m; m *= r;
            }
        } else {
            #pragma unroll
            for (int i = 0; i < 16; ++i) {
                const int l = ch * 16 + i;
                arrU[DEPIDX(col, l)] = lv[i] + m; m *= r;
            }
        }
    }
    __syncthreads();

    // ---- phase 3: entropy partial over this slab's 16x256 bins
    const float* fD = reinterpret_cast<const float*>(&dep[0]);
    float hsum = 0.0f;
    #pragma unroll
    for (int t = 0; t < 8; ++t) {
        const int q = tid + t * NT;
        const int c = q & 15, l = q >> 4;
        const int idx = DEPIDX(c, l);
        const float b  = fD[idx] + arrU[idx];
        const float ph = b * (1.0f / 16384.0f);
        hsum -= ph * (__builtin_amdgcn_logf(ph + 1e-6f) * LN2);
    }
    #pragma unroll
    for (int off = 32; off > 0; off >>= 1) hsum += __shfl_down(hsum, off);
    if ((tid & 63) == 0) wred[tid >> 6] = hsum;
    __syncthreads();
    if (tid == 0) {
        float tot = 0.0f;
        #pragma unroll
        for (int w = 0; w < 8; ++w) tot += wred[w];
        partials[wg] = tot;
    }
}

__global__ __launch_bounds__(256)
void bq_finish(const float* __restrict__ partials, float* __restrict__ ent_out)
{
    const int tid = threadIdx.x;
    float v = partials[tid] + partials[tid + 256];
    #pragma unroll
    for (int off = 32; off > 0; off >>= 1) v += __shfl_down(v, off);
    __shared__ float buf[4];
    if ((tid & 63) == 0) buf[tid >> 6] = v;
    __syncthreads();
    if (tid == 0) ent_out[0] = buf[0] + buf[1] + buf[2] + buf[3];
}

extern "C" void kernel_launch(void* const* d_in, const int* in_sizes, int n_in,
                              void* d_out, int out_size, void* d_ws, size_t ws_size,
                              hipStream_t stream)
{
    const float* Wt  = (const float*)d_in[0];
    const float* wmn = (const float*)d_in[1];
    const float* wmx = (const float*)d_in[2];
    float* out = (float*)d_out;      // [1048576 dequant] + [1 entropy]
    float* partials = (float*)d_ws;  // 512 floats

    bq_main<<<512, NT, 0, stream>>>(Wt, wmn, wmx, out, partials);
    bq_finish<<<1, 256, 0, stream>>>(partials, out + 1048576);
}

// Round 7
// 11.787 us; speedup vs baseline: 1.8275x; 1.0556x over previous
//
#include <hip/hip_runtime.h>
#include <math.h>

// BlockwiseQuantizationOptim: 1024x1024 f32, 64 blocks of 128x128, L=256, T=100.
// Closed-form softmax over uniform levels: e_l = r^|p-l|, r = exp(-100/255).
//   S  = rf*A[k] + r1f*A[j],  j = 254-k
//   W  = rf*(k*A[k]-B[k]) + r1f*((k+1)*A[j]+B[j])
// tab4[k] = (A[k], k*A[k]-B[k], A[j], (k+1)*A[j]+B[j])  (trans-free init via
// bit-product powers of r).
// bin_mass: ONE ds_add_u32 per element packing down-seed (level k, bits 0..15)
// and up-seed (level k+1, bits 16..31) as 8.8 fixed point (per-bin half-sums
// <= 32768 < 2^16; u32 is the only native-fast LDS atomic — R2/R4 evidence).
// Phases 2+3 FUSED in-register: one thread per (col, 8-level chunk) computes
// both geometric scans from 9 packed reads + two width-32 shfl carry scans,
// then entropy terms directly. No arrU, no scan writes, 3 barriers total.
// Two-kernel finish — no device-scope fences/atomics in the hot kernel
// (R4/R5 regression).
//
// dep LDS layout: idx(c,l) = (l&15)*272 + c*17 + (l>>4)

#define NT 512
#define LVL 256
#define PSC 256.0f                // 8 fraction bits
#define INV_PSC (1.0f / 256.0f)
#define DEPIDX(c, l) ((((l) & 15) * 272) + ((c) * 17) + ((l) >> 4))
#define NDEP 4352

__global__ __launch_bounds__(NT)
void bq_main(const float* __restrict__ Wt,
             const float* __restrict__ wmin_in,
             const float* __restrict__ wmax_in,
             float* __restrict__ dq_out,
             float* __restrict__ partials)
{
    __shared__ float4 tab4[LVL];
    __shared__ unsigned dep[NDEP];   // packed {lo: dn@l, hi: up@l+1}
    __shared__ float wred[8];

    const int tid = threadIdx.x;
    const int wg  = blockIdx.x;
    const int n = wg >> 3, slab = wg & 7;   // block 0..63, 16-col slab 0..7

    // ---- prefetch: issue global loads first, hide init under them (T14)
    const int row = tid >> 2;              // 0..127
    const int c0  = (tid & 3) * 4;         // 0,4,8,12
    const int R = (n >> 3) * 128 + row;
    const int C = (n & 7) * 128 + slab * 16 + c0;
    const float4 x4 = *reinterpret_cast<const float4*>(Wt + (size_t)R * 1024 + C);
    const float bmn = wmin_in[n], bmx = wmax_in[n];

    const float LN2 = 0.69314718055994531f;
    const float L2R = -(100.0f / 255.0f) * 1.4426950408889634f;  // log2(r)
    const float r = __builtin_amdgcn_exp2f(L2R);
    const float inv1mr = 1.0f / (1.0f - r);

    // ---- table init, transcendental-free: r^e via bit-product of r^(2^b)
    if (tid < LVL) {
        float rb[9];
        rb[0] = r;
        #pragma unroll
        for (int b = 1; b < 9; ++b) rb[b] = rb[b - 1] * rb[b - 1];
        const unsigned e1 = tid + 1;          // r^(k+1), 1..256
        const unsigned e2 = (~tid) & 255u;    // r^(255-k)
        float rk1 = 1.0f, rj1 = 1.0f;
        #pragma unroll
        for (int b = 0; b < 9; ++b) if ((e1 >> b) & 1u) rk1 *= rb[b];
        #pragma unroll
        for (int b = 0; b < 8; ++b) if ((e2 >> b) & 1u) rj1 *= rb[b];
        const float k  = (float)tid;
        const float Ak = (1.0f - rk1) * inv1mr;
        const float Bk = (r - (k + 1.0f) * rk1 + k * rk1 * r) * (inv1mr * inv1mr);
        const float Aj = (1.0f - rj1) * inv1mr;
        const float Bj = (r - (255.0f - k) * rj1 + (254.0f - k) * rj1 * r)
                         * (inv1mr * inv1mr);
        tab4[tid] = make_float4(Ak, k * Ak - Bk, Aj, (k + 1.0f) * Aj + Bj);
    }
    for (int q = tid; q < NDEP; q += NT) dep[q] = 0u;

    const float wmn = fminf(bmn, bmx - 1e-6f);
    const float wmx = fmaxf(bmx, wmn + 1e-6f);
    const float scale = wmx - wmn;
    const float invsc = 255.0f / (scale + 1e-6f);
    const float sc255 = scale * (1.0f / 255.0f);

    __syncthreads();

    // ---- phase 1: closed-form softmax + dequant + 1 packed u32 deposit/elem
    {
        float xs[4] = {x4.x, x4.y, x4.z, x4.w};
        float dq[4];
        #pragma unroll
        for (int u = 0; u < 4; ++u) {
            const float p = (xs[u] - wmn) * invsc;   // in [0,255)
            int k = (int)p; k = (k > 254) ? 254 : k;
            const float f   = p - (float)k;
            const float rf  = __builtin_amdgcn_exp2f(L2R * f);
            const float r1f = __builtin_amdgcn_exp2f(L2R * (1.0f - f));
            const float4 t = tab4[k];
            const float S  = rf * t.x + r1f * t.z;
            const float Wn = rf * t.y + r1f * t.w;
            const float invS = __builtin_amdgcn_rcpf(S);
            dq[u] = Wn * invS * sc255 + wmn;
            const unsigned dn = (unsigned)(rf  * invS * PSC + 0.5f);
            const unsigned up = (unsigned)(r1f * invS * PSC + 0.5f);
            atomicAdd(&dep[DEPIDX(c0 + u, k)], dn | (up << 16));
        }
        float4 o4; o4.x = dq[0]; o4.y = dq[1]; o4.z = dq[2]; o4.w = dq[3];
        *reinterpret_cast<float4*>(dq_out + (size_t)R * 1024 + C) = o4;
    }
    __syncthreads();

    // ---- fused phases 2+3: thread = (col 0..15, chunk 0..31), 8 levels each.
    // D[l] = sum_{k>=l} dn_k r^(k-l)   (lo halves, hi->lo)
    // U[l] = sum_{j<=l} up_j r^(l-j)   (hi half of word j-1 is up@j, lo->hi)
    // Local register scans + width-32 Hillis-Steele carry scans (both dirs),
    // then entropy terms in-register. dep is read-only here.
    float hsum = 0.0f;
    {
        const int col = tid >> 5;
        const int ch  = tid & 31;
        const int l0  = ch * 8;
        unsigned wd[9];
        wd[0] = (ch > 0) ? dep[DEPIDX(col, l0 - 1)] : 0u;
        #pragma unroll
        for (int j = 0; j < 8; ++j) wd[j + 1] = dep[DEPIDX(col, l0 + j)];

        float lvD[8], lvU[8];
        float vD = 0.0f;
        #pragma unroll
        for (int i = 7; i >= 0; --i) {
            vD = vD * r + (float)(wd[i + 1] & 0xffffu) * INV_PSC;
            lvD[i] = vD;
        }
        float vU = 0.0f;
        #pragma unroll
        for (int i = 0; i < 8; ++i) {
            vU = vU * r + (float)(wd[i] >> 16) * INV_PSC;
            lvU[i] = vU;
        }
        // cross-chunk carries, both directions in one pass
        float r8 = r * r; r8 = r8 * r8; r8 = r8 * r8;   // r^8
        float uD = vD, uU = vU, rp = r8;
        #pragma unroll
        for (int s = 1; s <= 16; s <<= 1) {
            const float oD = __shfl_down(uD, s, 32);
            const float oU = __shfl_up(uU, s, 32);
            if (ch + s < 32) uD += rp * oD;
            if (ch >= s)     uU += rp * oU;
            rp *= rp;
        }
        const float cvD = (ch < 31) ? __shfl_down(uD, 1, 32) : 0.0f;  // D[l0+8]
        const float cvU = (ch > 0)  ? __shfl_up(uU, 1, 32)  : 0.0f;   // U[l0-1]

        float DD[8];
        float m = cvD * r;
        #pragma unroll
        for (int i = 7; i >= 0; --i) { DD[i] = lvD[i] + m; m *= r; }
        m = cvU * r;
        #pragma unroll
        for (int i = 0; i < 8; ++i) {
            const float b  = DD[i] + lvU[i] + m; m *= r;
            const float ph = b * (1.0f / 16384.0f);
            hsum -= ph * (__builtin_amdgcn_logf(ph + 1e-6f) * LN2);
        }
    }
    #pragma unroll
    for (int off = 32; off > 0; off >>= 1) hsum += __shfl_down(hsum, off);
    if ((tid & 63) == 0) wred[tid >> 6] = hsum;
    __syncthreads();
    if (tid == 0) {
        float tot = 0.0f;
        #pragma unroll
        for (int w = 0; w < 8; ++w) tot += wred[w];
        partials[wg] = tot;
    }
}

__global__ __launch_bounds__(256)
void bq_finish(const float* __restrict__ partials, float* __restrict__ ent_out)
{
    const int tid = threadIdx.x;
    float v = partials[tid] + partials[tid + 256];
    #pragma unroll
    for (int off = 32; off > 0; off >>= 1) v += __shfl_down(v, off);
    __shared__ float buf[4];
    if ((tid & 63) == 0) buf[tid >> 6] = v;
    __syncthreads();
    if (tid == 0) ent_out[0] = buf[0] + buf[1] + buf[2] + buf[3];
}

extern "C" void kernel_launch(void* const* d_in, const int* in_sizes, int n_in,
                              void* d_out, int out_size, void* d_ws, size_t ws_size,
                              hipStream_t stream)
{
    const float* Wt  = (const float*)d_in[0];
    const float* wmn = (const float*)d_in[1];
    const float* wmx = (const float*)d_in[2];
    float* out = (float*)d_out;      // [1048576 dequant] + [1 entropy]
    float* partials = (float*)d_ws;  // 512 floats

    bq_main<<<512, NT, 0, stream>>>(Wt, wmn, wmx, out, partials);
    bq_finish<<<1, 256, 0, stream>>>(partials, out + 1048576);
}